// Round 1
// baseline (97.916 us; speedup 1.0000x reference)
//
#include <hip/hip_runtime.h>
#include <hip/hip_bf16.h>

// Problem constants (from setup_inputs): price_data float32 [64, 4096, 64]
#define B 64
#define S 4096
#define C 64
#define NCHUNK 32            // s-chunks per batch in phase1
#define LCH (S / NCHUNK)     // 128 s per block
#define WAVES 4              // 256-thread blocks
#define SPW (LCH / WAVES)    // 32 s per wave

// Partials layout in ws: part[p][ (b*NCHUNK + chunk)*64 + c ], p in [0,6)
// p: 0=sum, 1=sumsq, 2=gain, 3=loss, 4=sum12, 5=sum26
#define PSTRIDE ((size_t)B * NCHUNK * 64)   // 131072 floats per partial plane

// Phase 1: per-(b,chunk) partial reductions. Fully coalesced: lane = channel c.
__global__ __launch_bounds__(256) void ti_phase1(const float* __restrict__ x,
                                                 float* __restrict__ part) {
    const int b     = blockIdx.x / NCHUNK;
    const int chunk = blockIdx.x % NCHUNK;
    const int tid   = threadIdx.x;
    const int w     = tid >> 6;     // wave 0..3
    const int c     = tid & 63;     // channel (lane)
    const int s0    = chunk * LCH + w * SPW;

    const float* base = x + ((size_t)b * S) * C + c;

    float sum = 0.f, sumsq = 0.f, gain = 0.f, loss = 0.f, s12 = 0.f, s26 = 0.f;
    // prev value for delta at the wave's first s (delta_s = x[s] - x[s-1], s>=1)
    float prev = (s0 > 0) ? base[(size_t)(s0 - 1) * C] : 0.f;

    #pragma unroll 4
    for (int s = s0; s < s0 + SPW; ++s) {
        float v = base[(size_t)s * C];
        sum   += v;
        sumsq += v * v;
        if (s > 0) {
            float d = v - prev;
            gain += fmaxf(d, 0.f);
            loss += fmaxf(-d, 0.f);
        }
        prev = v;
        if (s >= S - 26) {
            s26 += v;
            if (s >= S - 12) s12 += v;
        }
    }

    // Cross-wave reduce in LDS: lds[p][w][c]; lane stride 4B -> 2-way alias (free)
    __shared__ float lds[6][WAVES][64];
    lds[0][w][c] = sum;  lds[1][w][c] = sumsq;
    lds[2][w][c] = gain; lds[3][w][c] = loss;
    lds[4][w][c] = s12;  lds[5][w][c] = s26;
    __syncthreads();

    if (tid < 64) {
        const size_t idx = ((size_t)(b * NCHUNK + chunk)) * 64 + c;
        #pragma unroll
        for (int p = 0; p < 6; ++p) {
            float t = lds[p][0][c] + lds[p][1][c] + lds[p][2][c] + lds[p][3][c];
            part[(size_t)p * PSTRIDE + idx] = t;
        }
    }
}

// Phase 2: fold chunks, compute the four broadcast stats per (b,c).
// stats layout: stats[which][b*64 + c], which: 0=rsi 1=macd 2=upper 3=lower
__global__ __launch_bounds__(64) void ti_phase2(const float* __restrict__ part,
                                                float* __restrict__ stats) {
    const int b = blockIdx.x;
    const int c = threadIdx.x;

    float acc[6] = {0.f, 0.f, 0.f, 0.f, 0.f, 0.f};
    for (int ch = 0; ch < NCHUNK; ++ch) {
        const size_t idx = ((size_t)(b * NCHUNK + ch)) * 64 + c;
        #pragma unroll
        for (int p = 0; p < 6; ++p) acc[p] += part[(size_t)p * PSTRIDE + idx];
    }

    const float sum = acc[0], sumsq = acc[1], gain = acc[2], loss = acc[3];
    const float s12 = acc[4], s26 = acc[5];

    const float inv_sm1 = 1.f / (float)(S - 1);
    const float ag = gain * inv_sm1;
    const float al = loss * inv_sm1;
    const float rs = ag / (al + 1e-7f);
    const float rsi = 100.f - 100.f / (1.f + rs);

    const float macd = s12 * (1.f / 12.f) - s26 * (1.f / 26.f);

    const float sma = sum * (1.f / (float)S);
    const float var = sumsq * (1.f / (float)S) - sma * sma;
    const float sd = sqrtf(fmaxf(var, 0.f));
    const float upper = sma + 2.f * sd;
    const float lower = sma - 2.f * sd;

    const int o = b * 64 + c;
    stats[0 * (B * C) + o] = rsi;
    stats[1 * (B * C) + o] = macd;
    stats[2 * (B * C) + o] = upper;
    stats[3 * (B * C) + o] = lower;
}

// Phase 3: write the full output with float4 stores.
// Output row (b,s) = 320 floats = 80 float4: q<16 -> input copy, else stats.
__global__ __launch_bounds__(256) void ti_phase3(const float4* __restrict__ in4,
                                                 const float4* __restrict__ stats4,
                                                 float4* __restrict__ out4) {
    const int ROWQ = 80;
    const size_t total = (size_t)B * S * ROWQ;  // 20,971,520
    const size_t stride = (size_t)gridDim.x * blockDim.x;
    for (size_t i = (size_t)blockIdx.x * blockDim.x + threadIdx.x; i < total; i += stride) {
        const size_t row = i / ROWQ;      // b*S + s
        const int q = (int)(i - row * ROWQ);
        float4 v;
        if (q < 16) {
            v = in4[row * 16 + q];
        } else {
            const int qq = q - 16;
            const int which = qq >> 4;          // 0..3
            const int c4 = qq & 15;             // float4 index within channel group
            const size_t b = row >> 12;         // row / S
            v = stats4[(size_t)which * (B * C / 4) + b * 16 + c4];
        }
        out4[i] = v;
    }
}

extern "C" void kernel_launch(void* const* d_in, const int* in_sizes, int n_in,
                              void* d_out, int out_size, void* d_ws, size_t ws_size,
                              hipStream_t stream) {
    const float* x = (const float*)d_in[0];
    float* out = (float*)d_out;
    float* ws = (float*)d_ws;

    float* part  = ws;                       // 6 * 131072 floats = 3 MB
    float* stats = ws + 6 * PSTRIDE;         // 4 * 4096 floats = 64 KB

    ti_phase1<<<B * NCHUNK, 256, 0, stream>>>(x, part);
    ti_phase2<<<B, 64, 0, stream>>>(part, stats);
    ti_phase3<<<2048, 256, 0, stream>>>((const float4*)x, (const float4*)stats,
                                        (float4*)out);
}

// Round 3
// 89.107 us; speedup vs baseline: 1.0989x; 1.0989x over previous
//
#include <hip/hip_runtime.h>
#include <hip/hip_bf16.h>

// Problem constants (from setup_inputs): price_data float32 [64, 4096, 64]
#define B 64
#define S 4096
#define C 64
#define NCHUNK 32            // s-chunks per batch in phase1
#define LCH (S / NCHUNK)     // 128 s per block
#define WAVES 4              // 256-thread blocks
#define SPW (LCH / WAVES)    // 32 s per wave

// native clang vector type (usable with __builtin_nontemporal_store)
typedef float f32x4 __attribute__((ext_vector_type(4)));

// Partials layout in ws: part[p][ (b*NCHUNK + chunk)*64 + c ], p in [0,6)
// p: 0=sum, 1=sumsq, 2=gain, 3=loss, 4=sum12, 5=sum26
#define PSTRIDE ((size_t)B * NCHUNK * 64)   // 131072 floats per partial plane

// Phase 1: per-(b,chunk) partial reductions. Fully coalesced: lane = channel c.
__global__ __launch_bounds__(256) void ti_phase1(const float* __restrict__ x,
                                                 float* __restrict__ part) {
    const int b     = blockIdx.x / NCHUNK;
    const int chunk = blockIdx.x % NCHUNK;
    const int tid   = threadIdx.x;
    const int w     = tid >> 6;     // wave 0..3
    const int c     = tid & 63;     // channel (lane)
    const int s0    = chunk * LCH + w * SPW;

    const float* base = x + ((size_t)b * S) * C + c;

    float sum = 0.f, sumsq = 0.f, gain = 0.f, loss = 0.f, s12 = 0.f, s26 = 0.f;
    // prev value for delta at the wave's first s (delta_s = x[s] - x[s-1], s>=1)
    float prev = (s0 > 0) ? base[(size_t)(s0 - 1) * C] : 0.f;

    #pragma unroll 4
    for (int s = s0; s < s0 + SPW; ++s) {
        float v = base[(size_t)s * C];
        sum   += v;
        sumsq += v * v;
        if (s > 0) {
            float d = v - prev;
            gain += fmaxf(d, 0.f);
            loss += fmaxf(-d, 0.f);
        }
        prev = v;
        if (s >= S - 26) {
            s26 += v;
            if (s >= S - 12) s12 += v;
        }
    }

    // Cross-wave reduce in LDS: lds[p][w][c]; lane stride 4B -> 2-way alias (free)
    __shared__ float lds[6][WAVES][64];
    lds[0][w][c] = sum;  lds[1][w][c] = sumsq;
    lds[2][w][c] = gain; lds[3][w][c] = loss;
    lds[4][w][c] = s12;  lds[5][w][c] = s26;
    __syncthreads();

    if (tid < 64) {
        const size_t idx = ((size_t)(b * NCHUNK + chunk)) * 64 + c;
        #pragma unroll
        for (int p = 0; p < 6; ++p) {
            float t = lds[p][0][c] + lds[p][1][c] + lds[p][2][c] + lds[p][3][c];
            part[(size_t)p * PSTRIDE + idx] = t;
        }
    }
}

// Phase 2: fold chunks, compute the four broadcast stats per (b,c).
// stats layout: stats[which][b*64 + c], which: 0=rsi 1=macd 2=upper 3=lower
__global__ __launch_bounds__(64) void ti_phase2(const float* __restrict__ part,
                                                float* __restrict__ stats) {
    const int b = blockIdx.x;
    const int c = threadIdx.x;

    float acc[6] = {0.f, 0.f, 0.f, 0.f, 0.f, 0.f};
    for (int ch = 0; ch < NCHUNK; ++ch) {
        const size_t idx = ((size_t)(b * NCHUNK + ch)) * 64 + c;
        #pragma unroll
        for (int p = 0; p < 6; ++p) acc[p] += part[(size_t)p * PSTRIDE + idx];
    }

    const float sum = acc[0], sumsq = acc[1], gain = acc[2], loss = acc[3];
    const float s12 = acc[4], s26 = acc[5];

    const float inv_sm1 = 1.f / (float)(S - 1);
    const float ag = gain * inv_sm1;
    const float al = loss * inv_sm1;
    const float rs = ag / (al + 1e-7f);
    const float rsi = 100.f - 100.f / (1.f + rs);

    const float macd = s12 * (1.f / 12.f) - s26 * (1.f / 26.f);

    const float sma = sum * (1.f / (float)S);
    const float var = sumsq * (1.f / (float)S) - sma * sma;
    const float sd = sqrtf(fmaxf(var, 0.f));
    const float upper = sma + 2.f * sd;
    const float lower = sma - 2.f * sd;

    const int o = b * 64 + c;
    stats[0 * (B * C) + o] = rsi;
    stats[1 * (B * C) + o] = macd;
    stats[2 * (B * C) + o] = upper;
    stats[3 * (B * C) + o] = lower;
}

// Phase 3: write the full output with float4 nontemporal stores.
// Output row (b,s) = 80 float4: [0,16) = input copy, [16,80) = stats broadcast.
// Two grid-stride loops with power-of-2 per-row counts -> shift/mask addressing,
// no integer division.
__global__ __launch_bounds__(256) void ti_phase3(const f32x4* __restrict__ in4,
                                                 const f32x4* __restrict__ stats4,
                                                 f32x4* __restrict__ out4) {
    const size_t tid0   = (size_t)blockIdx.x * blockDim.x + threadIdx.x;
    const size_t stride = (size_t)gridDim.x * blockDim.x;

    // --- copy region: 16 float4 per row, load is linear in4[i] ---
    {
        const size_t total = (size_t)B * S * 16;   // 4,194,304
        for (size_t i = tid0; i < total; i += stride) {
            const size_t row = i >> 4;
            const int q = (int)(i & 15);
            __builtin_nontemporal_store(in4[i], &out4[row * 80 + q]);
        }
    }

    // --- broadcast region: 64 float4 per row ---
    {
        const size_t total = (size_t)B * S * 64;   // 16,777,216
        for (size_t i = tid0; i < total; i += stride) {
            const size_t row = i >> 6;              // b*S + s
            const int q = (int)(i & 63);
            const int which = q >> 4;               // 0..3
            const int c4 = q & 15;                  // float4 within channel group
            const size_t b = row >> 12;             // row / S
            const f32x4 v = stats4[(size_t)which * (B * C / 4) + b * 16 + c4];
            __builtin_nontemporal_store(v, &out4[row * 80 + 16 + q]);
        }
    }
}

extern "C" void kernel_launch(void* const* d_in, const int* in_sizes, int n_in,
                              void* d_out, int out_size, void* d_ws, size_t ws_size,
                              hipStream_t stream) {
    const float* x = (const float*)d_in[0];
    float* out = (float*)d_out;
    float* ws = (float*)d_ws;

    float* part  = ws;                       // 6 * 131072 floats = 3 MB
    float* stats = ws + 6 * PSTRIDE;         // 4 * 4096 floats = 64 KB

    ti_phase1<<<B * NCHUNK, 256, 0, stream>>>(x, part);
    ti_phase2<<<B, 64, 0, stream>>>(part, stats);
    ti_phase3<<<2048, 256, 0, stream>>>((const f32x4*)x, (const f32x4*)stats,
                                        (f32x4*)out);
}

// Round 4
// 82.426 us; speedup vs baseline: 1.1879x; 1.0810x over previous
//
#include <hip/hip_runtime.h>
#include <hip/hip_bf16.h>

// Problem constants (from setup_inputs): price_data float32 [64, 4096, 64]
#define B 64
#define S 4096
#define C 64
#define NCHUNK 32            // s-chunks per batch in the copy+reduce kernel
#define LCH (S / NCHUNK)     // 128 s per block
#define SPT (LCH / 16)       // 8 s per thread-slice (16 slices per block)

// native clang vector type (usable with __builtin_nontemporal_store)
typedef float f32x4 __attribute__((ext_vector_type(4)));

// Partials layout in ws: part[p][ (b*NCHUNK + chunk)*64 + c ], p in [0,6)
// p: 0=sum, 1=sumsq, 2=gain, 3=loss, 4=sum12, 5=sum26
#define PSTRIDE ((size_t)B * NCHUNK * 64)   // 131072 floats per partial plane

__device__ inline f32x4 vmax0(f32x4 a) {
    f32x4 r;
    r.x = fmaxf(a.x, 0.f);
    r.y = fmaxf(a.y, 0.f);
    r.z = fmaxf(a.z, 0.f);
    r.w = fmaxf(a.w, 0.f);
    return r;
}

// Kernel A: fused input-copy (out channels [0,64)) + partial reductions.
// Thread layout: tid = slice*16 + c4; each thread owns 4 channels (c4*4..+3)
// over a contiguous run of SPT=8 s values. 16B/lane loads & stores, fully
// coalesced in 256B runs per 16-lane group.
__global__ __launch_bounds__(256) void ti_copy_reduce(const f32x4* __restrict__ in4,
                                                      f32x4* __restrict__ out4,
                                                      float* __restrict__ part) {
    const int b     = blockIdx.x / NCHUNK;
    const int chunk = blockIdx.x % NCHUNK;
    const int tid   = threadIdx.x;
    const int sl    = tid >> 4;     // s-slice 0..15
    const int c4    = tid & 15;     // float4 channel group 0..15
    const int s0    = chunk * LCH + sl * SPT;

    const size_t rowbase = (size_t)b * S;

    f32x4 sum = {0,0,0,0}, sumsq = {0,0,0,0}, gain = {0,0,0,0}, loss = {0,0,0,0};
    f32x4 s12 = {0,0,0,0}, s26 = {0,0,0,0};

    f32x4 prev = {0,0,0,0};
    if (s0 > 0) prev = in4[(rowbase + s0 - 1) * 16 + c4];

    #pragma unroll
    for (int j = 0; j < SPT; ++j) {
        const int s = s0 + j;
        const size_t r = rowbase + s;
        const f32x4 v = in4[r * 16 + c4];
        __builtin_nontemporal_store(v, &out4[r * 80 + c4]);   // copy region
        sum   += v;
        sumsq += v * v;
        if (s > 0) {
            const f32x4 d = v - prev;
            gain += vmax0(d);
            loss += vmax0(-d);
        }
        prev = v;
        if (s >= S - 26) {
            s26 += v;
            if (s >= S - 12) s12 += v;
        }
    }

    // Cross-slice reduce in LDS: lds[p][sl][ch], ch = c4*4+k
    __shared__ float lds[6][16][64];
    *(f32x4*)&lds[0][sl][c4 * 4] = sum;
    *(f32x4*)&lds[1][sl][c4 * 4] = sumsq;
    *(f32x4*)&lds[2][sl][c4 * 4] = gain;
    *(f32x4*)&lds[3][sl][c4 * 4] = loss;
    *(f32x4*)&lds[4][sl][c4 * 4] = s12;
    *(f32x4*)&lds[5][sl][c4 * 4] = s26;
    __syncthreads();

    if (tid < 64) {
        const size_t idx = ((size_t)(b * NCHUNK + chunk)) * 64 + tid;
        #pragma unroll
        for (int p = 0; p < 6; ++p) {
            float t = 0.f;
            #pragma unroll
            for (int s2 = 0; s2 < 16; ++s2) t += lds[p][s2][tid];
            part[(size_t)p * PSTRIDE + idx] = t;
        }
    }
}

// Kernel B: fold chunks, compute the four broadcast stats per (b,c).
// stats layout: stats[which][b*64 + c], which: 0=rsi 1=macd 2=upper 3=lower
__global__ __launch_bounds__(64) void ti_stats(const float* __restrict__ part,
                                               float* __restrict__ stats) {
    const int b = blockIdx.x;
    const int c = threadIdx.x;

    float acc[6] = {0.f, 0.f, 0.f, 0.f, 0.f, 0.f};
    for (int ch = 0; ch < NCHUNK; ++ch) {
        const size_t idx = ((size_t)(b * NCHUNK + ch)) * 64 + c;
        #pragma unroll
        for (int p = 0; p < 6; ++p) acc[p] += part[(size_t)p * PSTRIDE + idx];
    }

    const float sum = acc[0], sumsq = acc[1], gain = acc[2], loss = acc[3];
    const float s12 = acc[4], s26 = acc[5];

    const float inv_sm1 = 1.f / (float)(S - 1);
    const float ag = gain * inv_sm1;
    const float al = loss * inv_sm1;
    const float rs = ag / (al + 1e-7f);
    const float rsi = 100.f - 100.f / (1.f + rs);

    const float macd = s12 * (1.f / 12.f) - s26 * (1.f / 26.f);

    const float sma = sum * (1.f / (float)S);
    const float var = sumsq * (1.f / (float)S) - sma * sma;
    const float sd = sqrtf(fmaxf(var, 0.f));
    const float upper = sma + 2.f * sd;
    const float lower = sma - 2.f * sd;

    const int o = b * 64 + c;
    stats[0 * (B * C) + o] = rsi;
    stats[1 * (B * C) + o] = macd;
    stats[2 * (B * C) + o] = upper;
    stats[3 * (B * C) + o] = lower;
}

// Kernel C: broadcast writer for out channels [64,320): 256 MB of nontemporal
// stores from a 64 KB L2-resident stats table. Grid stride (524288) divides
// the per-row quantity (64), so q/which/c4 are loop-invariant; exactly 32
// iterations per thread, no tail.
#define GRID_C 2048
__global__ __launch_bounds__(256) void ti_broadcast(const f32x4* __restrict__ stats4,
                                                    f32x4* __restrict__ out4) {
    const size_t stride = (size_t)GRID_C * 256;          // 524288, % 64 == 0
    size_t i = (size_t)blockIdx.x * blockDim.x + threadIdx.x;

    const int q     = (int)(i & 63);   // loop-invariant
    const int which = q >> 4;          // 0..3
    const int c4    = q & 15;
    const f32x4* sp = stats4 + (size_t)which * (B * C / 4) + c4;

    #pragma unroll 4
    for (int it = 0; it < 32; ++it, i += stride) {
        const size_t row = i >> 6;             // b*S + s
        const size_t b   = i >> 18;            // row / S
        const f32x4 v = sp[b * 16];
        __builtin_nontemporal_store(v, &out4[row * 80 + 16 + q]);
    }
}

extern "C" void kernel_launch(void* const* d_in, const int* in_sizes, int n_in,
                              void* d_out, int out_size, void* d_ws, size_t ws_size,
                              hipStream_t stream) {
    const float* x = (const float*)d_in[0];
    float* out = (float*)d_out;
    float* ws = (float*)d_ws;

    float* part  = ws;                       // 6 * 131072 floats = 3 MB
    float* stats = ws + 6 * PSTRIDE;         // 4 * 4096 floats = 64 KB

    ti_copy_reduce<<<B * NCHUNK, 256, 0, stream>>>((const f32x4*)x, (f32x4*)out, part);
    ti_stats<<<B, 64, 0, stream>>>(part, stats);
    ti_broadcast<<<GRID_C, 256, 0, stream>>>((const f32x4*)stats, (f32x4*)out);
}